// Round 11
// baseline (265.597 us; speedup 1.0000x reference)
//
#include <hip/hip_runtime.h>
#include <math.h>

#define NEG_SLOPE 0.2f
#define CAP 128     // max in-edges/node in LDS; deg~Binom(640K,1/20K) mean 32, max ~58
#define ST  136     // padded head stride (floats): hh*136%32 = hh*8 -> conflict-free
#define NNODES 20000
#define NB 128      // counting-sort blocks (LDS histogram per block); chunk=5000

typedef short s16x8 __attribute__((ext_vector_type(8)));
typedef unsigned short us8 __attribute__((ext_vector_type(8)));
typedef float f32x4 __attribute__((ext_vector_type(4)));

__device__ __forceinline__ unsigned short f2bf(float f) {
    unsigned int u = __float_as_uint(f);
    return (unsigned short)((u + 0x7FFFu + ((u >> 16) & 1u)) >> 16);
}
__device__ __forceinline__ float bf2f(unsigned short s) {
    return __uint_as_float(((unsigned int)s) << 16);
}

// ==================== bf16 MFMA GEMM core + fused asrc/adst epilogue ====================
// C16[M,256] = bf16(A*B^T). A from A16 (bf16) or A32 (fp32, converted in staging —
// bitwise-identical rounding to a precomputed bf16 copy). B from Bt16 (transposed bf16)
// or B32 (fp32 [K][256] row-major, transposed+converted in staging; tile is L2-hot).
// [verified C/D map: col=lane&15, row=quad*4+reg]
__device__ __forceinline__ void gemm_core(const unsigned short* __restrict__ A16,
                                          const float* __restrict__ A32,
                                          const unsigned short* __restrict__ Bt16,
                                          const float* __restrict__ B32,
                                          unsigned short* __restrict__ C16,
                                          const float* __restrict__ a_src,
                                          const float* __restrict__ a_dst,
                                          float* __restrict__ asrc,
                                          float* __restrict__ adst,
                                          int M, int K, int bx, int by,
                                          unsigned short (*As)[40],
                                          unsigned short (*Bs)[40]) {
    const int tid = threadIdx.x;
    const int w = tid >> 6, l = tid & 63;
    const int quad = l >> 4, m16 = l & 15;
    const int row0 = by * 128, col0 = bx * 64;

    f32x4 acc[2][4] = {};

    const int a_r = tid >> 1;
    const int a_k = (tid & 1) * 16;
    const int b_n = tid >> 2;
    const int b_k = (tid & 3) * 8;

    for (int k0 = 0; k0 < K; k0 += 32) {
        int gr = row0 + a_r; if (gr > M - 1) gr = M - 1;
        if (A32) {
            const float* ap = A32 + (size_t)gr * K + k0 + a_k;
            float4 f0 = *(const float4*)(ap);
            float4 f1 = *(const float4*)(ap + 4);
            float4 f2 = *(const float4*)(ap + 8);
            float4 f3 = *(const float4*)(ap + 12);
            unsigned short* d0 = &As[a_r][a_k];
            d0[0] = f2bf(f0.x); d0[1] = f2bf(f0.y); d0[2] = f2bf(f0.z); d0[3] = f2bf(f0.w);
            d0[4] = f2bf(f1.x); d0[5] = f2bf(f1.y); d0[6] = f2bf(f1.z); d0[7] = f2bf(f1.w);
            d0[8] = f2bf(f2.x); d0[9] = f2bf(f2.y); d0[10] = f2bf(f2.z); d0[11] = f2bf(f2.w);
            d0[12] = f2bf(f3.x); d0[13] = f2bf(f3.y); d0[14] = f2bf(f3.z); d0[15] = f2bf(f3.w);
        } else {
            const unsigned short* ap = A16 + (size_t)gr * K + k0 + a_k;
            *(us8*)&As[a_r][a_k]     = *(const us8*)ap;
            *(us8*)&As[a_r][a_k + 8] = *(const us8*)(ap + 8);
        }
        if (B32) {
            const float* bp = B32 + (size_t)(k0 + b_k) * 256 + col0 + b_n;
            unsigned short t[8];
#pragma unroll
            for (int j = 0; j < 8; ++j) t[j] = f2bf(bp[(size_t)j * 256]);
            *(us8*)&Bs[b_n][b_k] = *(const us8*)t;
        } else {
            *(us8*)&Bs[b_n][b_k] = *(const us8*)(Bt16 + (size_t)(col0 + b_n) * K + k0 + b_k);
        }
        __syncthreads();

        s16x8 af[2], bfr[4];
#pragma unroll
        for (int mt = 0; mt < 2; ++mt)
            af[mt] = *(const s16x8*)&As[w * 32 + mt * 16 + m16][quad * 8];
#pragma unroll
        for (int nt = 0; nt < 4; ++nt)
            bfr[nt] = *(const s16x8*)&Bs[nt * 16 + m16][quad * 8];
#pragma unroll
        for (int mt = 0; mt < 2; ++mt)
#pragma unroll
            for (int nt = 0; nt < 4; ++nt)
                acc[mt][nt] = __builtin_amdgcn_mfma_f32_16x16x32_bf16(af[mt], bfr[nt], acc[mt][nt], 0, 0, 0);
        __syncthreads();
    }

    const int h = bx;
    float was[4], wad[4];
#pragma unroll
    for (int nt = 0; nt < 4; ++nt) {
        int c = nt * 16 + m16;
        was[nt] = a_src[h * 64 + c];
        wad[nt] = a_dst[h * 64 + c];
    }

#pragma unroll
    for (int mt = 0; mt < 2; ++mt)
#pragma unroll
        for (int i = 0; i < 4; ++i) {
            int row = row0 + w * 32 + mt * 16 + quad * 4 + i;
            float ps = 0.f, pd = 0.f;
#pragma unroll
            for (int nt = 0; nt < 4; ++nt) {
                float v = acc[mt][nt][i];
                ps += v * was[nt];
                pd += v * wad[nt];
            }
#pragma unroll
            for (int ofs = 1; ofs < 16; ofs <<= 1) {
                ps += __shfl_xor(ps, ofs);
                pd += __shfl_xor(pd, ofs);
            }
            if (m16 == 0 && row < M) {
                asrc[(size_t)row * 4 + h] = ps;
                adst[(size_t)row * 4 + h] = pd;
            }
        }

#pragma unroll
    for (int mt = 0; mt < 2; ++mt)
#pragma unroll
        for (int nt = 0; nt < 4; ++nt) {
            int col = col0 + nt * 16 + m16;
#pragma unroll
            for (int i = 0; i < 4; ++i) {
                int row = row0 + w * 32 + mt * 16 + quad * 4 + i;
                if (row < M) C16[(size_t)row * 256 + col] = f2bf(acc[mt][nt][i]);
            }
        }
}

// ==================== K1: hist ∥ gemm1 (fp32-staged, no prep dependency) ∥ prep ========
// blocks [0,histB): 16-bit packed LDS histogram (40KB smem).
// blocks [histB, histB+gemmB): layer-1 GEMM, A=x fp32, B=W1 fp32 (convert in staging).
// blocks [histB+gemmB, +32): Wt2 transpose + ce. All independent -> full overlap.
__global__ __launch_bounds__(256) void hist_gemm1_prep(const int* __restrict__ dst,
                                                       int* __restrict__ ghist,
                                                       int E, int chunk, int N,
                                                       int histB, int gemmB,
                                                       const float* __restrict__ x,
                                                       const float* __restrict__ W1,
                                                       const float* __restrict__ W2,
                                                       const float* __restrict__ W_e1,
                                                       const float* __restrict__ a_e1,
                                                       const float* __restrict__ W_e2,
                                                       const float* __restrict__ a_e2,
                                                       unsigned short* __restrict__ Wt2,
                                                       float* __restrict__ ce,
                                                       unsigned short* __restrict__ xh16,
                                                       const float* __restrict__ a_src1,
                                                       const float* __restrict__ a_dst1,
                                                       float* __restrict__ asrc,
                                                       float* __restrict__ adst,
                                                       int M) {
    __shared__ int smem[NNODES / 2];   // 40000B: hist uses all; gemm aliases 15360B
    if ((int)blockIdx.x < histB) {
        const int b = blockIdx.x;
        const int NH = N >> 1;
        for (int i = threadIdx.x; i < NH; i += 256) smem[i] = 0;
        __syncthreads();
        const int e0 = b * chunk;
        const int e1 = min(e0 + chunk, E);
        for (int e = e0 + (int)threadIdx.x; e < e1; e += 256) {
            int d = dst[e];
            atomicAdd(&smem[d >> 1], 1 << ((d & 1) << 4));   // LDS atomic, block-local
        }
        __syncthreads();
        int2* out = (int2*)(ghist + (size_t)b * N);
        for (int i = threadIdx.x; i < NH; i += 256) {
            int v = smem[i];
            out[i] = make_int2(v & 0xFFFF, ((unsigned)v) >> 16);
        }
    } else if ((int)blockIdx.x < histB + gemmB) {
        int g = (int)blockIdx.x - histB;
        gemm_core((const unsigned short*)nullptr, x, (const unsigned short*)nullptr, W1,
                  xh16, a_src1, a_dst1, asrc, adst, M, 128, g & 3, g >> 2,
                  (unsigned short(*)[40])smem,
                  (unsigned short(*)[40])((char*)smem + 10240));
    } else {
        const int p = (int)blockIdx.x - histB - gemmB;   // 0..31
        const int gsz = 32 * 256;
        const int gid = p * 256 + (int)threadIdx.x;
        for (int i = gid; i < 256 * 256; i += gsz) {
            int k = i >> 8, n = i & 255;
            Wt2[n * 256 + k] = f2bf(W2[i]);
        }
        if (p < 2) {
            const float* We = p == 0 ? W_e1 : W_e2;
            const float* ae = p == 0 ? a_e1 : a_e2;
            int hh = threadIdx.x >> 6, c = threadIdx.x & 63;
            float pr = We[hh * 64 + c] * ae[hh * 64 + c];
#pragma unroll
            for (int off = 32; off > 0; off >>= 1) pr += __shfl_down(pr, off);
            if (c == 0) ce[p * 4 + hh] = pr;
        }
    }
}

// ==================== K2: column-prefix of ghist -> per-block offsets + deg ============
__global__ __launch_bounds__(256) void colscan(int* __restrict__ ghist,
                                               int* __restrict__ deg,
                                               int N, int histB) {
    int bin = blockIdx.x * 256 + (int)threadIdx.x;
    if (bin < N) {
        int run = 0;
        for (int b = 0; b < histB; b += 8) {   // histB % 8 == 0
            int v[8];
#pragma unroll
            for (int j = 0; j < 8; ++j) v[j] = ghist[(b + j) * N + bin];
#pragma unroll
            for (int j = 0; j < 8; ++j) { ghist[(b + j) * N + bin] = run; run += v[j]; }
        }
        deg[bin] = run;
    }
}

// ==================== K3: fill + in-block deg->off scan (scan kernel folded in) ========
__global__ __launch_bounds__(1024) void fill_scan(const int* __restrict__ src,
                                                  const int* __restrict__ dst,
                                                  const float* __restrict__ edge_attr,
                                                  const float* __restrict__ edge_atten,
                                                  const int* __restrict__ deg,
                                                  const int* __restrict__ ghist,
                                                  int* __restrict__ off_out,
                                                  int4* __restrict__ rec,
                                                  int E, int chunk, int N) {
    __shared__ int base[NNODES];
    __shared__ int wsum[16];
    __shared__ int woff[16];
    __shared__ int s_carry, s_bt;
    if (threadIdx.x == 0) s_carry = 0;
    __syncthreads();
    const int lane = threadIdx.x & 63, wid = threadIdx.x >> 6;
    for (int bb = 0; bb < N; bb += 4096) {
        int i0 = bb + (int)threadIdx.x * 4;
        int v0 = (i0 + 0 < N) ? deg[i0 + 0] : 0;
        int v1 = (i0 + 1 < N) ? deg[i0 + 1] : 0;
        int v2 = (i0 + 2 < N) ? deg[i0 + 2] : 0;
        int v3 = (i0 + 3 < N) ? deg[i0 + 3] : 0;
        int tsum = v0 + v1 + v2 + v3;
        int incl = tsum;
#pragma unroll
        for (int ofs = 1; ofs < 64; ofs <<= 1) {
            int t = __shfl_up(incl, ofs);
            if (lane >= ofs) incl += t;
        }
        if (lane == 63) wsum[wid] = incl;
        __syncthreads();
        if (wid == 0) {
            int ws = (lane < 16) ? wsum[lane] : 0;
            int wincl = ws;
#pragma unroll
            for (int ofs = 1; ofs < 16; ofs <<= 1) {
                int t = __shfl_up(wincl, ofs);
                if (lane >= ofs) wincl += t;
            }
            if (lane < 16) woff[lane] = wincl - ws;
            if (lane == 15) s_bt = wincl;
        }
        __syncthreads();
        int e0 = s_carry + woff[wid] + incl - tsum;
        int e1 = e0 + v0, e2 = e1 + v1, e3 = e2 + v2;
        if (i0 + 0 < N) base[i0 + 0] = e0;
        if (i0 + 1 < N) base[i0 + 1] = e1;
        if (i0 + 2 < N) base[i0 + 2] = e2;
        if (i0 + 3 < N) base[i0 + 3] = e3;
        __syncthreads();
        if (threadIdx.x == 0) s_carry += s_bt;
        __syncthreads();
    }
    if (blockIdx.x == 0) {
        for (int i = threadIdx.x; i < N; i += 1024) off_out[i] = base[i];
        if (threadIdx.x == 0) off_out[N] = s_carry;
    }
    const int b = blockIdx.x;
    const int* part = ghist + (size_t)b * N;
    for (int i = threadIdx.x; i < N; i += 1024) base[i] += part[i];
    __syncthreads();
    const int e0c = b * chunk;
    const int e1c = min(e0c + chunk, E);
    for (int e = e0c + (int)threadIdx.x; e < e1c; e += 1024) {
        int d = dst[e];
        int pos = atomicAdd(&base[d], 1);       // LDS atomic — unique global slot
        rec[pos] = make_int4(src[e], e, __float_as_int(edge_attr[e]),
                             __float_as_int(edge_atten[e]));
    }
}

// ==================== fused per-node softmax + aggregation (R7-exact) ====================
__global__ __launch_bounds__(256) void node_fused(const int4* __restrict__ rec,
                                                  const int* __restrict__ off,
                                                  const float* __restrict__ asrc,
                                                  const float* __restrict__ adst,
                                                  const float* __restrict__ ce,
                                                  const unsigned short* __restrict__ xh16,
                                                  const float* __restrict__ bias,
                                                  float* __restrict__ w,       // scratch + (if write_w) output
                                                  int write_w,
                                                  float* __restrict__ mxrc,            // nullable
                                                  float* __restrict__ houtf,           // nullable
                                                  unsigned short* __restrict__ hout16, // nullable
                                                  int N) {
    __shared__ float s_al[4][4][ST];
    __shared__ int s_src[4][CAP];
    const int wid = threadIdx.x >> 6;
    const int n = blockIdx.x * 4 + wid;
    if (n >= N) return;
    const int lane = threadIdx.x & 63;
    float* al = &s_al[wid][0][0];
    int* sv = s_src[wid];
    const int o0 = off[n], o1 = off[n + 1];
    const int deg = o1 - o0;

    const float4 c4 = *(const float4*)ce;
    const float4 ad4 = *(const float4*)(adst + (size_t)n * 4);

    if (deg <= 64) {
        int4 r; float4 a;
        a.x = a.y = a.z = a.w = -3.4e38f;
        if (lane < deg) {
            r = rec[o0 + lane];
            float ea = __int_as_float(r.z);
            const float4 as4 = *(const float4*)(asrc + (size_t)r.x * 4);
            a.x = as4.x + ad4.x + ea * c4.x;
            a.y = as4.y + ad4.y + ea * c4.y;
            a.z = as4.z + ad4.z + ea * c4.z;
            a.w = as4.w + ad4.w + ea * c4.w;
            a.x = a.x > 0.f ? a.x : NEG_SLOPE * a.x;
            a.y = a.y > 0.f ? a.y : NEG_SLOPE * a.y;
            a.z = a.z > 0.f ? a.z : NEG_SLOPE * a.z;
            a.w = a.w > 0.f ? a.w : NEG_SLOPE * a.w;
        }
        float4 mx = a;
#pragma unroll
        for (int ofs = 1; ofs < 64; ofs <<= 1) {
            mx.x = fmaxf(mx.x, __shfl_xor(mx.x, ofs));
            mx.y = fmaxf(mx.y, __shfl_xor(mx.y, ofs));
            mx.z = fmaxf(mx.z, __shfl_xor(mx.z, ofs));
            mx.w = fmaxf(mx.w, __shfl_xor(mx.w, ofs));
        }
        float4 ex = make_float4(0.f, 0.f, 0.f, 0.f);
        if (lane < deg) {
            ex.x = __expf(a.x - mx.x);
            ex.y = __expf(a.y - mx.y);
            ex.z = __expf(a.z - mx.z);
            ex.w = __expf(a.w - mx.w);
        }
        float4 sm = ex;
#pragma unroll
        for (int ofs = 1; ofs < 64; ofs <<= 1) {
            sm.x += __shfl_xor(sm.x, ofs);
            sm.y += __shfl_xor(sm.y, ofs);
            sm.z += __shfl_xor(sm.z, ofs);
            sm.w += __shfl_xor(sm.w, ofs);
        }
        float4 rc;
        rc.x = 1.f / (sm.x + 1e-16f);
        rc.y = 1.f / (sm.y + 1e-16f);
        rc.z = 1.f / (sm.z + 1e-16f);
        rc.w = 1.f / (sm.w + 1e-16f);
        if (mxrc && lane == 0) {
            *(float4*)(mxrc + (size_t)n * 8) = mx;
            *(float4*)(mxrc + (size_t)n * 8 + 4) = rc;
        }
        if (lane < deg) {
            float4 aln;
            aln.x = ex.x * rc.x;
            aln.y = ex.y * rc.y;
            aln.z = ex.z * rc.z;
            aln.w = ex.w * rc.w;
            if (write_w) *(float4*)(w + (size_t)r.y * 4) = aln;
            float att = __int_as_float(r.w);
            sv[lane] = r.x;
            al[0 * ST + lane] = aln.x * att;
            al[1 * ST + lane] = aln.y * att;
            al[2 * ST + lane] = aln.z * att;
            al[3 * ST + lane] = aln.w * att;
        }
    } else {
        float4 mx = make_float4(-3.4e38f, -3.4e38f, -3.4e38f, -3.4e38f);
        for (int idx = lane; idx < deg; idx += 64) {
            int4 r = rec[o0 + idx];
            float ea = __int_as_float(r.z);
            const float4 as4 = *(const float4*)(asrc + (size_t)r.x * 4);
            float4 a;
            a.x = as4.x + ad4.x + ea * c4.x;
            a.y = as4.y + ad4.y + ea * c4.y;
            a.z = as4.z + ad4.z + ea * c4.z;
            a.w = as4.w + ad4.w + ea * c4.w;
            a.x = a.x > 0.f ? a.x : NEG_SLOPE * a.x;
            a.y = a.y > 0.f ? a.y : NEG_SLOPE * a.y;
            a.z = a.z > 0.f ? a.z : NEG_SLOPE * a.z;
            a.w = a.w > 0.f ? a.w : NEG_SLOPE * a.w;
            if (idx < CAP) {
                sv[idx] = r.x;
                al[0 * ST + idx] = a.x;
                al[1 * ST + idx] = a.y;
                al[2 * ST + idx] = a.z;
                al[3 * ST + idx] = a.w;
            } else {
                *(float4*)(w + (size_t)r.y * 4) = a;
            }
            mx.x = fmaxf(mx.x, a.x);
            mx.y = fmaxf(mx.y, a.y);
            mx.z = fmaxf(mx.z, a.z);
            mx.w = fmaxf(mx.w, a.w);
        }
#pragma unroll
        for (int ofs = 1; ofs < 64; ofs <<= 1) {
            mx.x = fmaxf(mx.x, __shfl_xor(mx.x, ofs));
            mx.y = fmaxf(mx.y, __shfl_xor(mx.y, ofs));
            mx.z = fmaxf(mx.z, __shfl_xor(mx.z, ofs));
            mx.w = fmaxf(mx.w, __shfl_xor(mx.w, ofs));
        }
        float4 sm = make_float4(0.f, 0.f, 0.f, 0.f);
        for (int idx = lane; idx < deg; idx += 64) {
            float4 a;
            int espill = -1;
            if (idx < CAP) {
                a.x = al[0 * ST + idx];
                a.y = al[1 * ST + idx];
                a.z = al[2 * ST + idx];
                a.w = al[3 * ST + idx];
            } else {
                espill = rec[o0 + idx].y;
                a = *(const float4*)(w + (size_t)espill * 4);
            }
            a.x = __expf(a.x - mx.x);
            a.y = __expf(a.y - mx.y);
            a.z = __expf(a.z - mx.z);
            a.w = __expf(a.w - mx.w);
            if (idx < CAP) {
                al[0 * ST + idx] = a.x;
                al[1 * ST + idx] = a.y;
                al[2 * ST + idx] = a.z;
                al[3 * ST + idx] = a.w;
            } else {
                *(float4*)(w + (size_t)espill * 4) = a;
            }
            sm.x += a.x; sm.y += a.y; sm.z += a.z; sm.w += a.w;
        }
#pragma unroll
        for (int ofs = 1; ofs < 64; ofs <<= 1) {
            sm.x += __shfl_xor(sm.x, ofs);
            sm.y += __shfl_xor(sm.y, ofs);
            sm.z += __shfl_xor(sm.z, ofs);
            sm.w += __shfl_xor(sm.w, ofs);
        }
        float4 rc;
        rc.x = 1.f / (sm.x + 1e-16f);
        rc.y = 1.f / (sm.y + 1e-16f);
        rc.z = 1.f / (sm.z + 1e-16f);
        rc.w = 1.f / (sm.w + 1e-16f);
        if (mxrc && lane == 0) {
            *(float4*)(mxrc + (size_t)n * 8) = mx;
            *(float4*)(mxrc + (size_t)n * 8 + 4) = rc;
        }
        for (int idx = lane; idx < deg; idx += 64) {
            int4 r = rec[o0 + idx];
            float4 ex;
            if (idx < CAP) {
                ex.x = al[0 * ST + idx];
                ex.y = al[1 * ST + idx];
                ex.z = al[2 * ST + idx];
                ex.w = al[3 * ST + idx];
            } else {
                ex = *(const float4*)(w + (size_t)r.y * 4);
            }
            float4 aln;
            aln.x = ex.x * rc.x;
            aln.y = ex.y * rc.y;
            aln.z = ex.z * rc.z;
            aln.w = ex.w * rc.w;
            *(float4*)(w + (size_t)r.y * 4) = aln;
            if (idx < CAP) {
                float att = __int_as_float(r.w);
                al[0 * ST + idx] = aln.x * att;
                al[1 * ST + idx] = aln.y * att;
                al[2 * ST + idx] = aln.z * att;
                al[3 * ST + idx] = aln.w * att;
            }
        }
    }

    // phase 4: aggregation, lane = channel (4 ch/lane), 8-edge unroll (8 loads in flight)
    const int hh = lane >> 4;
    const float* alh = al + hh * ST;
    float4 a0 = *(const float4*)(bias + lane * 4);
    float4 a1 = make_float4(0.f, 0.f, 0.f, 0.f);
    float4 a2 = a1, a3 = a1;
    const int kmax = deg < CAP ? deg : CAP;
    int k = 0;
    for (; k + 8 <= kmax; k += 8) {
        int4 s4a = *(const int4*)&sv[k];
        int4 s4b = *(const int4*)&sv[k + 4];
        float4 ca = *(const float4*)&alh[k];
        float4 cb = *(const float4*)&alh[k + 4];
        ushort4 u0 = *((const ushort4*)(xh16 + (size_t)s4a.x * 256) + lane);
        ushort4 u1 = *((const ushort4*)(xh16 + (size_t)s4a.y * 256) + lane);
        ushort4 u2 = *((const ushort4*)(xh16 + (size_t)s4a.z * 256) + lane);
        ushort4 u3 = *((const ushort4*)(xh16 + (size_t)s4a.w * 256) + lane);
        ushort4 u4 = *((const ushort4*)(xh16 + (size_t)s4b.x * 256) + lane);
        ushort4 u5 = *((const ushort4*)(xh16 + (size_t)s4b.y * 256) + lane);
        ushort4 u6 = *((const ushort4*)(xh16 + (size_t)s4b.z * 256) + lane);
        ushort4 u7 = *((const ushort4*)(xh16 + (size_t)s4b.w * 256) + lane);
        a0.x += bf2f(u0.x) * ca.x; a0.y += bf2f(u0.y) * ca.x; a0.z += bf2f(u0.z) * ca.x; a0.w += bf2f(u0.w) * ca.x;
        a1.x += bf2f(u1.x) * ca.y; a1.y += bf2f(u1.y) * ca.y; a1.z += bf2f(u1.z) * ca.y; a1.w += bf2f(u1.w) * ca.y;
        a2.x += bf2f(u2.x) * ca.z; a2.y += bf2f(u2.y) * ca.z; a2.z += bf2f(u2.z) * ca.z; a2.w += bf2f(u2.w) * ca.z;
        a3.x += bf2f(u3.x) * ca.w; a3.y += bf2f(u3.y) * ca.w; a3.z += bf2f(u3.z) * ca.w; a3.w += bf2f(u3.w) * ca.w;
        a0.x += bf2f(u4.x) * cb.x; a0.y += bf2f(u4.y) * cb.x; a0.z += bf2f(u4.z) * cb.x; a0.w += bf2f(u4.w) * cb.x;
        a1.x += bf2f(u5.x) * cb.y; a1.y += bf2f(u5.y) * cb.y; a1.z += bf2f(u5.z) * cb.y; a1.w += bf2f(u5.w) * cb.y;
        a2.x += bf2f(u6.x) * cb.z; a2.y += bf2f(u6.y) * cb.z; a2.z += bf2f(u6.z) * cb.z; a2.w += bf2f(u6.w) * cb.z;
        a3.x += bf2f(u7.x) * cb.w; a3.y += bf2f(u7.y) * cb.w; a3.z += bf2f(u7.z) * cb.w; a3.w += bf2f(u7.w) * cb.w;
    }
    for (; k + 4 <= kmax; k += 4) {
        int4 s4 = *(const int4*)&sv[k];
        float4 cc = *(const float4*)&alh[k];
        ushort4 u0 = *((const ushort4*)(xh16 + (size_t)s4.x * 256) + lane);
        ushort4 u1 = *((const ushort4*)(xh16 + (size_t)s4.y * 256) + lane);
        ushort4 u2 = *((const ushort4*)(xh16 + (size_t)s4.z * 256) + lane);
        ushort4 u3 = *((const ushort4*)(xh16 + (size_t)s4.w * 256) + lane);
        a0.x += bf2f(u0.x) * cc.x; a0.y += bf2f(u0.y) * cc.x; a0.z += bf2f(u0.z) * cc.x; a0.w += bf2f(u0.w) * cc.x;
        a1.x += bf2f(u1.x) * cc.y; a1.y += bf2f(u1.y) * cc.y; a1.z += bf2f(u1.z) * cc.y; a1.w += bf2f(u1.w) * cc.y;
        a2.x += bf2f(u2.x) * cc.z; a2.y += bf2f(u2.y) * cc.z; a2.z += bf2f(u2.z) * cc.z; a2.w += bf2f(u2.w) * cc.z;
        a3.x += bf2f(u3.x) * cc.w; a3.y += bf2f(u3.y) * cc.w; a3.z += bf2f(u3.z) * cc.w; a3.w += bf2f(u3.w) * cc.w;
    }
    for (; k < kmax; ++k) {
        int s = sv[k];
        float sc = alh[k];
        ushort4 uv = *((const ushort4*)(xh16 + (size_t)s * 256) + lane);
        a0.x += bf2f(uv.x) * sc; a0.y += bf2f(uv.y) * sc;
        a0.z += bf2f(uv.z) * sc; a0.w += bf2f(uv.w) * sc;
    }
    for (k = CAP; k < deg; ++k) {   // rare spill path
        int4 r = rec[o0 + k];
        float sc = w[(size_t)r.y * 4 + hh] * __int_as_float(r.w);
        ushort4 uv = *((const ushort4*)(xh16 + (size_t)r.x * 256) + lane);
        a0.x += bf2f(uv.x) * sc; a0.y += bf2f(uv.y) * sc;
        a0.z += bf2f(uv.z) * sc; a0.w += bf2f(uv.w) * sc;
    }
    float4 acc;
    acc.x = (a0.x + a1.x) + (a2.x + a3.x);
    acc.y = (a0.y + a1.y) + (a2.y + a3.y);
    acc.z = (a0.z + a1.z) + (a2.z + a3.z);
    acc.w = (a0.w + a1.w) + (a2.w + a3.w);
    if (houtf)  *(float4*)(houtf + (size_t)n * 256 + lane * 4) = acc;
    if (hout16) {
        ushort4 u = make_ushort4(f2bf(acc.x), f2bf(acc.y), f2bf(acc.z), f2bf(acc.w));
        *((ushort4*)(hout16 + (size_t)n * 256) + lane) = u;
    }
}

// ==================== K5: gemm layer2 ∥ edge-major w1 reconstruction ====================
__global__ __launch_bounds__(256) void gemm2_w1(const unsigned short* __restrict__ A16,
                                                const unsigned short* __restrict__ Bt16,
                                                unsigned short* __restrict__ C16,
                                                const float* __restrict__ a_src,
                                                const float* __restrict__ a_dst,
                                                float* __restrict__ asrc2,
                                                float* __restrict__ adst2,
                                                int M, int K, int gemmB,
                                                const int* __restrict__ src,
                                                const int* __restrict__ dstp,
                                                const float* __restrict__ edge_attr,
                                                const float* __restrict__ asrc1,
                                                const float* __restrict__ adst1,
                                                const float* __restrict__ mxrc,
                                                const float* __restrict__ ce1,
                                                float* __restrict__ w1, int E) {
    __shared__ unsigned short As[128][40];
    __shared__ unsigned short Bs[64][40];
    if ((int)blockIdx.x < gemmB) {
        gemm_core(A16, (const float*)nullptr, Bt16, (const float*)nullptr,
                  C16, a_src, a_dst, asrc2, adst2, M, K,
                  blockIdx.x & 3, blockIdx.x >> 2, As, Bs);
    } else {
        const int stride = ((int)gridDim.x - gemmB) * 256;
        const float4 c4 = *(const float4*)ce1;
        for (int e = ((int)blockIdx.x - gemmB) * 256 + (int)threadIdx.x; e < E; e += stride) {
            int s = src[e], d = dstp[e];
            float ea = edge_attr[e];
            const float4 as4 = *(const float4*)(asrc1 + (size_t)s * 4);
            const float4 ad4 = *(const float4*)(adst1 + (size_t)d * 4);
            float4 a;
            a.x = as4.x + ad4.x + ea * c4.x;
            a.y = as4.y + ad4.y + ea * c4.y;
            a.z = as4.z + ad4.z + ea * c4.z;
            a.w = as4.w + ad4.w + ea * c4.w;
            a.x = a.x > 0.f ? a.x : NEG_SLOPE * a.x;
            a.y = a.y > 0.f ? a.y : NEG_SLOPE * a.y;
            a.z = a.z > 0.f ? a.z : NEG_SLOPE * a.z;
            a.w = a.w > 0.f ? a.w : NEG_SLOPE * a.w;
            const float4 mx = *(const float4*)(mxrc + (size_t)d * 8);
            const float4 rc = *(const float4*)(mxrc + (size_t)d * 8 + 4);
            float4 o;
            o.x = __expf(a.x - mx.x) * rc.x;
            o.y = __expf(a.y - mx.y) * rc.y;
            o.z = __expf(a.z - mx.z) * rc.z;
            o.w = __expf(a.w - mx.w) * rc.w;
            *(float4*)(w1 + (size_t)e * 4) = o;
        }
    }
}

extern "C" void kernel_launch(void* const* d_in, const int* in_sizes, int n_in,
                              void* d_out, int out_size, void* d_ws, size_t ws_size,
                              hipStream_t stream) {
    const float* x          = (const float*)d_in[0];
    const int*   ei         = (const int*)d_in[1];
    const float* edge_attr  = (const float*)d_in[3];
    const float* edge_atten = (const float*)d_in[4];
    const float* W1     = (const float*)d_in[5];
    const float* a_src1 = (const float*)d_in[6];
    const float* a_dst1 = (const float*)d_in[7];
    const float* W_e1   = (const float*)d_in[8];
    const float* a_e1   = (const float*)d_in[9];
    const float* b1     = (const float*)d_in[10];
    const float* W2     = (const float*)d_in[11];
    const float* a_src2 = (const float*)d_in[12];
    const float* a_dst2 = (const float*)d_in[13];
    const float* W_e2   = (const float*)d_in[14];
    const float* a_e2   = (const float*)d_in[15];
    const float* b2     = (const float*)d_in[16];

    const int N = in_sizes[0] / 128;   // 20000
    const int E = in_sizes[1] / 2;     // 640000
    const int* srcp = ei;
    const int* dstp = ei + E;

    char* ws = (char*)d_ws;
    int4* rec             = (int4*)ws;            ws += (size_t)E * 16;       // 16B-aligned first
    unsigned short* xh16  = (unsigned short*)ws;  ws += (size_t)N * 256 * 2;
    unsigned short* h116  = (unsigned short*)ws;  ws += (size_t)N * 256 * 2;
    unsigned short* Wt2   = (unsigned short*)ws;  ws += (size_t)256 * 256 * 2;
    float* asrc   = (float*)ws;                   ws += (size_t)N * 4 * 4;
    float* adst   = (float*)ws;                   ws += (size_t)N * 4 * 4;
    float* asrc2  = (float*)ws;                   ws += (size_t)N * 4 * 4;
    float* adst2  = (float*)ws;                   ws += (size_t)N * 4 * 4;
    float* mxrc   = (float*)ws;                   ws += (size_t)N * 8 * 4;
    float* ce     = (float*)ws;                   ws += 32;   // ce1[4], ce2[4]
    int* deg    = (int*)ws;                       ws += (size_t)N * 4;
    int* off    = (int*)ws;                       ws += (size_t)(N + 1) * 4;
    int* ghist  = (int*)ws;                       ws += (size_t)NB * N * 4;   // 10.24 MB

    float* hout2 = (float*)d_out;                 // N*256
    float* w1    = hout2 + (size_t)N * 256;       // E*4
    float* w2    = w1 + (size_t)E * 4;            // E*4

    const int chunk = (E + NB - 1) / NB;          // 5000
    const int gb = (N + 3) / 4;
    const int rows = (N + 127) / 128;
    const int gemmB = 4 * rows;
    const int scanB = (N + 255) / 256;            // 79
    const int wB = 512;

    // ---------------- pipeline (hist ∥ gemm1 ∥ prep fused; no xb16/Wt1) ----------------
    hist_gemm1_prep<<<NB + gemmB + 32, 256, 0, stream>>>(dstp, ghist, E, chunk, N,
                                                         NB, gemmB,
                                                         x, W1, W2, W_e1, a_e1,
                                                         W_e2, a_e2, Wt2, ce,
                                                         xh16, a_src1, a_dst1,
                                                         asrc, adst, N);
    colscan<<<scanB, 256, 0, stream>>>(ghist, deg, N, NB);
    fill_scan<<<NB, 1024, 0, stream>>>(srcp, dstp, edge_attr, edge_atten,
                                       deg, ghist, off, rec, E, chunk, N);
    // layer-1 node pass: no w scatter; exports mx/rc per node
    node_fused<<<gb, 256, 0, stream>>>(rec, off, asrc, adst, ce, xh16, b1, w1,
                                       0, mxrc, (float*)nullptr, h116, N);
    // layer-2 gemm ∥ coalesced w1 reconstruction
    gemm2_w1<<<gemmB + wB, 256, 0, stream>>>(h116, Wt2, xh16, a_src2, a_dst2,
                                             asrc2, adst2, N, 256, gemmB,
                                             srcp, dstp, edge_attr,
                                             asrc, adst, mxrc, ce, w1, E);
    // layer-2 node pass: writes w2 directly + final output
    node_fused<<<gb, 256, 0, stream>>>(rec, off, asrc2, adst2, ce + 4, xh16, b2, w2,
                                       1, (float*)nullptr, hout2,
                                       (unsigned short*)nullptr, N);
}

// Round 12
// 251.672 us; speedup vs baseline: 1.0553x; 1.0553x over previous
//
#include <hip/hip_runtime.h>
#include <math.h>

#define NEG_SLOPE 0.2f
#define CAP 128     // max in-edges/node in LDS; deg~Binom(640K,1/20K) mean 32, max ~58
#define ST  136     // padded head stride (floats): hh*136%32 = hh*8 -> conflict-free
#define NNODES 20000
#define NB 128      // counting-sort blocks (LDS histogram per block); chunk=5000

typedef short s16x8 __attribute__((ext_vector_type(8)));
typedef unsigned short us8 __attribute__((ext_vector_type(8)));
typedef float f32x4 __attribute__((ext_vector_type(4)));

__device__ __forceinline__ unsigned short f2bf(float f) {
    unsigned int u = __float_as_uint(f);
    return (unsigned short)((u + 0x7FFFu + ((u >> 16) & 1u)) >> 16);
}
__device__ __forceinline__ float bf2f(unsigned short s) {
    return __uint_as_float(((unsigned int)s) << 16);
}

// ==================== K1: per-block LDS histogram (16-bit packed) ∥ prep ====================
__global__ __launch_bounds__(512) void hist_prep(const int* __restrict__ dst,
                                                 int* __restrict__ ghist,
                                                 int E, int chunk, int N, int histB,
                                                 const float* __restrict__ x,
                                                 const float* __restrict__ W1,
                                                 const float* __restrict__ W2,
                                                 const float* __restrict__ W_e1,
                                                 const float* __restrict__ a_e1,
                                                 const float* __restrict__ W_e2,
                                                 const float* __restrict__ a_e2,
                                                 unsigned short* __restrict__ xb16,
                                                 unsigned short* __restrict__ Wt1,
                                                 unsigned short* __restrict__ Wt2,
                                                 float* __restrict__ ce) {
    __shared__ int h[NNODES / 2];   // two 16-bit counters per word (chunk=5000 < 65536)
    if ((int)blockIdx.x < histB) {
        const int b = blockIdx.x;
        const int NH = N >> 1;
        for (int i = threadIdx.x; i < NH; i += 512) h[i] = 0;
        __syncthreads();
        const int e0 = b * chunk;
        const int e1 = min(e0 + chunk, E);
        for (int e = e0 + (int)threadIdx.x; e < e1; e += 512) {
            int d = dst[e];
            atomicAdd(&h[d >> 1], 1 << ((d & 1) << 4));   // LDS atomic, block-local
        }
        __syncthreads();
        int2* out = (int2*)(ghist + (size_t)b * N);
        for (int i = threadIdx.x; i < NH; i += 512) {
            int v = h[i];
            out[i] = make_int2(v & 0xFFFF, ((unsigned)v) >> 16);
        }
    } else {
        const int p = (int)blockIdx.x - histB;   // 0..255
        const int gsz = 256 * 512;
        const int gid = p * 512 + (int)threadIdx.x;
        for (int i = gid; i < 128 * 256; i += gsz) {
            int k = i >> 8, n = i & 255;
            Wt1[n * 128 + k] = f2bf(W1[i]);
        }
        for (int i = gid; i < 256 * 256; i += gsz) {
            int k = i >> 8, n = i & 255;
            Wt2[n * 256 + k] = f2bf(W2[i]);
        }
        for (int i = gid; i < N * 32; i += gsz) {
            float4 f = ((const float4*)x)[i];
            ushort4 u = make_ushort4(f2bf(f.x), f2bf(f.y), f2bf(f.z), f2bf(f.w));
            ((ushort4*)xb16)[i] = u;
        }
        if (p < 2 && threadIdx.x < 256) {
            const float* We = p == 0 ? W_e1 : W_e2;
            const float* ae = p == 0 ? a_e1 : a_e2;
            int hh = threadIdx.x >> 6, c = threadIdx.x & 63;
            float pr = We[hh * 64 + c] * ae[hh * 64 + c];
#pragma unroll
            for (int off = 32; off > 0; off >>= 1) pr += __shfl_down(pr, off);
            if (c == 0) ce[p * 4 + hh] = pr;
        }
    }
}

// ==================== bf16 MFMA GEMM core v2 + fused asrc/adst epilogue ====================
// 128x128 output tile (2 heads), BK=64 (32 MFMA per barrier pair), A re-read 2x not 4x.
// C16[M,256] = bf16(A16*Bt16^T). [verified C/D map: col=lane&15, row=quad*4+reg]
__device__ __forceinline__ void gemm_core(const unsigned short* __restrict__ A16,
                                          const unsigned short* __restrict__ Bt16,
                                          unsigned short* __restrict__ C16,
                                          const float* __restrict__ a_src,
                                          const float* __restrict__ a_dst,
                                          float* __restrict__ asrc,
                                          float* __restrict__ adst,
                                          int M, int K, int bx, int by,
                                          unsigned short (*As)[72],
                                          unsigned short (*Bs)[72]) {
    const int tid = threadIdx.x;
    const int w = tid >> 6, l = tid & 63;
    const int quad = l >> 4, m16 = l & 15;
    const int row0 = by * 128, col0 = bx * 128;

    f32x4 acc[2][8] = {};

    const int a_r = tid >> 1;           // 0..127: A row AND B col staged by this thread
    const int a_k = (tid & 1) * 32;     // 32 k-elems each

    for (int k0 = 0; k0 < K; k0 += 64) {
        int gr = row0 + a_r; if (gr > M - 1) gr = M - 1;
        const unsigned short* ap = A16 + (size_t)gr * K + k0 + a_k;
        *(us8*)&As[a_r][a_k]      = *(const us8*)ap;
        *(us8*)&As[a_r][a_k + 8]  = *(const us8*)(ap + 8);
        *(us8*)&As[a_r][a_k + 16] = *(const us8*)(ap + 16);
        *(us8*)&As[a_r][a_k + 24] = *(const us8*)(ap + 24);
        const unsigned short* bp = Bt16 + (size_t)(col0 + a_r) * K + k0 + a_k;
        *(us8*)&Bs[a_r][a_k]      = *(const us8*)bp;
        *(us8*)&Bs[a_r][a_k + 8]  = *(const us8*)(bp + 8);
        *(us8*)&Bs[a_r][a_k + 16] = *(const us8*)(bp + 16);
        *(us8*)&Bs[a_r][a_k + 24] = *(const us8*)(bp + 24);
        __syncthreads();

#pragma unroll
        for (int sub = 0; sub < 2; ++sub) {
            s16x8 af[2], bfr[8];
#pragma unroll
            for (int mt = 0; mt < 2; ++mt)
                af[mt] = *(const s16x8*)&As[w * 32 + mt * 16 + m16][sub * 32 + quad * 8];
#pragma unroll
            for (int nt = 0; nt < 8; ++nt)
                bfr[nt] = *(const s16x8*)&Bs[nt * 16 + m16][sub * 32 + quad * 8];
#pragma unroll
            for (int mt = 0; mt < 2; ++mt)
#pragma unroll
                for (int nt = 0; nt < 8; ++nt)
                    acc[mt][nt] = __builtin_amdgcn_mfma_f32_16x16x32_bf16(af[mt], bfr[nt], acc[mt][nt], 0, 0, 0);
        }
        __syncthreads();
    }

    const int h0 = col0 >> 6;   // two heads: h0, h0+1
    float was[8], wad[8];
#pragma unroll
    for (int nt = 0; nt < 8; ++nt) {
        int h = h0 + (nt >> 2);
        int c = (nt & 3) * 16 + m16;
        was[nt] = a_src[h * 64 + c];
        wad[nt] = a_dst[h * 64 + c];
    }

#pragma unroll
    for (int mt = 0; mt < 2; ++mt)
#pragma unroll
        for (int i = 0; i < 4; ++i) {
            int row = row0 + w * 32 + mt * 16 + quad * 4 + i;
#pragma unroll
            for (int p = 0; p < 2; ++p) {
                float ps = 0.f, pd = 0.f;
#pragma unroll
                for (int nt = p * 4; nt < p * 4 + 4; ++nt) {
                    float v = acc[mt][nt][i];
                    ps += v * was[nt];
                    pd += v * wad[nt];
                }
#pragma unroll
                for (int ofs = 1; ofs < 16; ofs <<= 1) {
                    ps += __shfl_xor(ps, ofs);
                    pd += __shfl_xor(pd, ofs);
                }
                if (m16 == 0 && row < M) {
                    asrc[(size_t)row * 4 + h0 + p] = ps;
                    adst[(size_t)row * 4 + h0 + p] = pd;
                }
            }
        }

#pragma unroll
    for (int mt = 0; mt < 2; ++mt)
#pragma unroll
        for (int nt = 0; nt < 8; ++nt) {
            int col = col0 + nt * 16 + m16;
#pragma unroll
            for (int i = 0; i < 4; ++i) {
                int row = row0 + w * 32 + mt * 16 + quad * 4 + i;
                if (row < M) C16[(size_t)row * 256 + col] = f2bf(acc[mt][nt][i]);
            }
        }
}

// ==================== K2: gemm layer1 ∥ column-prefix of ghist ====================
__global__ __launch_bounds__(256) void gemm1_scan(const unsigned short* __restrict__ A16,
                                                  const unsigned short* __restrict__ Bt16,
                                                  unsigned short* __restrict__ C16,
                                                  const float* __restrict__ a_src,
                                                  const float* __restrict__ a_dst,
                                                  float* __restrict__ asrc,
                                                  float* __restrict__ adst,
                                                  int M, int K, int gemmB,
                                                  int* __restrict__ ghist,
                                                  int* __restrict__ deg,
                                                  int N, int histB) {
    __shared__ unsigned short As[128][72];
    __shared__ unsigned short Bs[128][72];
    if ((int)blockIdx.x < gemmB) {
        gemm_core(A16, Bt16, C16, a_src, a_dst, asrc, adst, M, K,
                  blockIdx.x & 1, blockIdx.x >> 1, As, Bs);
    } else {
        int bin = ((int)blockIdx.x - gemmB) * 256 + (int)threadIdx.x;
        if (bin < N) {
            int run = 0;
            for (int b = 0; b < histB; b += 8) {   // histB % 8 == 0
                int v[8];
#pragma unroll
                for (int j = 0; j < 8; ++j) v[j] = ghist[(b + j) * N + bin];
#pragma unroll
                for (int j = 0; j < 8; ++j) { ghist[(b + j) * N + bin] = run; run += v[j]; }
            }
            deg[bin] = run;
        }
    }
}

// ==================== K3: fill + in-block deg->off scan (scan kernel folded in) ========
__global__ __launch_bounds__(1024) void fill_scan(const int* __restrict__ src,
                                                  const int* __restrict__ dst,
                                                  const float* __restrict__ edge_attr,
                                                  const float* __restrict__ edge_atten,
                                                  const int* __restrict__ deg,
                                                  const int* __restrict__ ghist,
                                                  int* __restrict__ off_out,
                                                  int4* __restrict__ rec,
                                                  int E, int chunk, int N) {
    __shared__ int base[NNODES];
    __shared__ int wsum[16];
    __shared__ int woff[16];
    __shared__ int s_carry, s_bt;
    if (threadIdx.x == 0) s_carry = 0;
    __syncthreads();
    const int lane = threadIdx.x & 63, wid = threadIdx.x >> 6;
    for (int bb = 0; bb < N; bb += 4096) {
        int i0 = bb + (int)threadIdx.x * 4;
        int v0 = (i0 + 0 < N) ? deg[i0 + 0] : 0;
        int v1 = (i0 + 1 < N) ? deg[i0 + 1] : 0;
        int v2 = (i0 + 2 < N) ? deg[i0 + 2] : 0;
        int v3 = (i0 + 3 < N) ? deg[i0 + 3] : 0;
        int tsum = v0 + v1 + v2 + v3;
        int incl = tsum;
#pragma unroll
        for (int ofs = 1; ofs < 64; ofs <<= 1) {
            int t = __shfl_up(incl, ofs);
            if (lane >= ofs) incl += t;
        }
        if (lane == 63) wsum[wid] = incl;
        __syncthreads();
        if (wid == 0) {
            int ws = (lane < 16) ? wsum[lane] : 0;
            int wincl = ws;
#pragma unroll
            for (int ofs = 1; ofs < 16; ofs <<= 1) {
                int t = __shfl_up(wincl, ofs);
                if (lane >= ofs) wincl += t;
            }
            if (lane < 16) woff[lane] = wincl - ws;
            if (lane == 15) s_bt = wincl;
        }
        __syncthreads();
        int e0 = s_carry + woff[wid] + incl - tsum;
        int e1 = e0 + v0, e2 = e1 + v1, e3 = e2 + v2;
        if (i0 + 0 < N) base[i0 + 0] = e0;
        if (i0 + 1 < N) base[i0 + 1] = e1;
        if (i0 + 2 < N) base[i0 + 2] = e2;
        if (i0 + 3 < N) base[i0 + 3] = e3;
        __syncthreads();
        if (threadIdx.x == 0) s_carry += s_bt;
        __syncthreads();
    }
    if (blockIdx.x == 0) {
        for (int i = threadIdx.x; i < N; i += 1024) off_out[i] = base[i];
        if (threadIdx.x == 0) off_out[N] = s_carry;
    }
    const int b = blockIdx.x;
    const int* part = ghist + (size_t)b * N;
    for (int i = threadIdx.x; i < N; i += 1024) base[i] += part[i];
    __syncthreads();
    const int e0c = b * chunk;
    const int e1c = min(e0c + chunk, E);
    for (int e = e0c + (int)threadIdx.x; e < e1c; e += 1024) {
        int d = dst[e];
        int pos = atomicAdd(&base[d], 1);       // LDS atomic — unique global slot
        rec[pos] = make_int4(src[e], e, __float_as_int(edge_attr[e]),
                             __float_as_int(edge_atten[e]));
    }
}

// ==================== fused per-node softmax + aggregation (R7-exact) ====================
__global__ __launch_bounds__(256) void node_fused(const int4* __restrict__ rec,
                                                  const int* __restrict__ off,
                                                  const float* __restrict__ asrc,
                                                  const float* __restrict__ adst,
                                                  const float* __restrict__ ce,
                                                  const unsigned short* __restrict__ xh16,
                                                  const float* __restrict__ bias,
                                                  float* __restrict__ w,       // scratch + (if write_w) output
                                                  int write_w,
                                                  float* __restrict__ mxrc,            // nullable
                                                  float* __restrict__ houtf,           // nullable
                                                  unsigned short* __restrict__ hout16, // nullable
                                                  int N) {
    __shared__ float s_al[4][4][ST];
    __shared__ int s_src[4][CAP];
    const int wid = threadIdx.x >> 6;
    const int n = blockIdx.x * 4 + wid;
    if (n >= N) return;
    const int lane = threadIdx.x & 63;
    float* al = &s_al[wid][0][0];
    int* sv = s_src[wid];
    const int o0 = off[n], o1 = off[n + 1];
    const int deg = o1 - o0;

    const float4 c4 = *(const float4*)ce;
    const float4 ad4 = *(const float4*)(adst + (size_t)n * 4);

    if (deg <= 64) {
        int4 r; float4 a;
        a.x = a.y = a.z = a.w = -3.4e38f;
        if (lane < deg) {
            r = rec[o0 + lane];
            float ea = __int_as_float(r.z);
            const float4 as4 = *(const float4*)(asrc + (size_t)r.x * 4);
            a.x = as4.x + ad4.x + ea * c4.x;
            a.y = as4.y + ad4.y + ea * c4.y;
            a.z = as4.z + ad4.z + ea * c4.z;
            a.w = as4.w + ad4.w + ea * c4.w;
            a.x = a.x > 0.f ? a.x : NEG_SLOPE * a.x;
            a.y = a.y > 0.f ? a.y : NEG_SLOPE * a.y;
            a.z = a.z > 0.f ? a.z : NEG_SLOPE * a.z;
            a.w = a.w > 0.f ? a.w : NEG_SLOPE * a.w;
        }
        float4 mx = a;
#pragma unroll
        for (int ofs = 1; ofs < 64; ofs <<= 1) {
            mx.x = fmaxf(mx.x, __shfl_xor(mx.x, ofs));
            mx.y = fmaxf(mx.y, __shfl_xor(mx.y, ofs));
            mx.z = fmaxf(mx.z, __shfl_xor(mx.z, ofs));
            mx.w = fmaxf(mx.w, __shfl_xor(mx.w, ofs));
        }
        float4 ex = make_float4(0.f, 0.f, 0.f, 0.f);
        if (lane < deg) {
            ex.x = __expf(a.x - mx.x);
            ex.y = __expf(a.y - mx.y);
            ex.z = __expf(a.z - mx.z);
            ex.w = __expf(a.w - mx.w);
        }
        float4 sm = ex;
#pragma unroll
        for (int ofs = 1; ofs < 64; ofs <<= 1) {
            sm.x += __shfl_xor(sm.x, ofs);
            sm.y += __shfl_xor(sm.y, ofs);
            sm.z += __shfl_xor(sm.z, ofs);
            sm.w += __shfl_xor(sm.w, ofs);
        }
        float4 rc;
        rc.x = 1.f / (sm.x + 1e-16f);
        rc.y = 1.f / (sm.y + 1e-16f);
        rc.z = 1.f / (sm.z + 1e-16f);
        rc.w = 1.f / (sm.w + 1e-16f);
        if (mxrc && lane == 0) {
            *(float4*)(mxrc + (size_t)n * 8) = mx;
            *(float4*)(mxrc + (size_t)n * 8 + 4) = rc;
        }
        if (lane < deg) {
            float4 aln;
            aln.x = ex.x * rc.x;
            aln.y = ex.y * rc.y;
            aln.z = ex.z * rc.z;
            aln.w = ex.w * rc.w;
            if (write_w) *(float4*)(w + (size_t)r.y * 4) = aln;
            float att = __int_as_float(r.w);
            sv[lane] = r.x;
            al[0 * ST + lane] = aln.x * att;
            al[1 * ST + lane] = aln.y * att;
            al[2 * ST + lane] = aln.z * att;
            al[3 * ST + lane] = aln.w * att;
        }
    } else {
        float4 mx = make_float4(-3.4e38f, -3.4e38f, -3.4e38f, -3.4e38f);
        for (int idx = lane; idx < deg; idx += 64) {
            int4 r = rec[o0 + idx];
            float ea = __int_as_float(r.z);
            const float4 as4 = *(const float4*)(asrc + (size_t)r.x * 4);
            float4 a;
            a.x = as4.x + ad4.x + ea * c4.x;
            a.y = as4.y + ad4.y + ea * c4.y;
            a.z = as4.z + ad4.z + ea * c4.z;
            a.w = as4.w + ad4.w + ea * c4.w;
            a.x = a.x > 0.f ? a.x : NEG_SLOPE * a.x;
            a.y = a.y > 0.f ? a.y : NEG_SLOPE * a.y;
            a.z = a.z > 0.f ? a.z : NEG_SLOPE * a.z;
            a.w = a.w > 0.f ? a.w : NEG_SLOPE * a.w;
            if (idx < CAP) {
                sv[idx] = r.x;
                al[0 * ST + idx] = a.x;
                al[1 * ST + idx] = a.y;
                al[2 * ST + idx] = a.z;
                al[3 * ST + idx] = a.w;
            } else {
                *(float4*)(w + (size_t)r.y * 4) = a;
            }
            mx.x = fmaxf(mx.x, a.x);
            mx.y = fmaxf(mx.y, a.y);
            mx.z = fmaxf(mx.z, a.z);
            mx.w = fmaxf(mx.w, a.w);
        }
#pragma unroll
        for (int ofs = 1; ofs < 64; ofs <<= 1) {
            mx.x = fmaxf(mx.x, __shfl_xor(mx.x, ofs));
            mx.y = fmaxf(mx.y, __shfl_xor(mx.y, ofs));
            mx.z = fmaxf(mx.z, __shfl_xor(mx.z, ofs));
            mx.w = fmaxf(mx.w, __shfl_xor(mx.w, ofs));
        }
        float4 sm = make_float4(0.f, 0.f, 0.f, 0.f);
        for (int idx = lane; idx < deg; idx += 64) {
            float4 a;
            int espill = -1;
            if (idx < CAP) {
                a.x = al[0 * ST + idx];
                a.y = al[1 * ST + idx];
                a.z = al[2 * ST + idx];
                a.w = al[3 * ST + idx];
            } else {
                espill = rec[o0 + idx].y;
                a = *(const float4*)(w + (size_t)espill * 4);
            }
            a.x = __expf(a.x - mx.x);
            a.y = __expf(a.y - mx.y);
            a.z = __expf(a.z - mx.z);
            a.w = __expf(a.w - mx.w);
            if (idx < CAP) {
                al[0 * ST + idx] = a.x;
                al[1 * ST + idx] = a.y;
                al[2 * ST + idx] = a.z;
                al[3 * ST + idx] = a.w;
            } else {
                *(float4*)(w + (size_t)espill * 4) = a;
            }
            sm.x += a.x; sm.y += a.y; sm.z += a.z; sm.w += a.w;
        }
#pragma unroll
        for (int ofs = 1; ofs < 64; ofs <<= 1) {
            sm.x += __shfl_xor(sm.x, ofs);
            sm.y += __shfl_xor(sm.y, ofs);
            sm.z += __shfl_xor(sm.z, ofs);
            sm.w += __shfl_xor(sm.w, ofs);
        }
        float4 rc;
        rc.x = 1.f / (sm.x + 1e-16f);
        rc.y = 1.f / (sm.y + 1e-16f);
        rc.z = 1.f / (sm.z + 1e-16f);
        rc.w = 1.f / (sm.w + 1e-16f);
        if (mxrc && lane == 0) {
            *(float4*)(mxrc + (size_t)n * 8) = mx;
            *(float4*)(mxrc + (size_t)n * 8 + 4) = rc;
        }
        for (int idx = lane; idx < deg; idx += 64) {
            int4 r = rec[o0 + idx];
            float4 ex;
            if (idx < CAP) {
                ex.x = al[0 * ST + idx];
                ex.y = al[1 * ST + idx];
                ex.z = al[2 * ST + idx];
                ex.w = al[3 * ST + idx];
            } else {
                ex = *(const float4*)(w + (size_t)r.y * 4);
            }
            float4 aln;
            aln.x = ex.x * rc.x;
            aln.y = ex.y * rc.y;
            aln.z = ex.z * rc.z;
            aln.w = ex.w * rc.w;
            *(float4*)(w + (size_t)r.y * 4) = aln;
            if (idx < CAP) {
                float att = __int_as_float(r.w);
                al[0 * ST + idx] = aln.x * att;
                al[1 * ST + idx] = aln.y * att;
                al[2 * ST + idx] = aln.z * att;
                al[3 * ST + idx] = aln.w * att;
            }
        }
    }

    // phase 4: aggregation, lane = channel (4 ch/lane), 8-edge unroll (8 loads in flight)
    const int hh = lane >> 4;
    const float* alh = al + hh * ST;
    float4 a0 = *(const float4*)(bias + lane * 4);
    float4 a1 = make_float4(0.f, 0.f, 0.f, 0.f);
    float4 a2 = a1, a3 = a1;
    const int kmax = deg < CAP ? deg : CAP;
    int k = 0;
    for (; k + 8 <= kmax; k += 8) {
        int4 s4a = *(const int4*)&sv[k];
        int4 s4b = *(const int4*)&sv[k + 4];
        float4 ca = *(const float4*)&alh[k];
        float4 cb = *(const float4*)&alh[k + 4];
        ushort4 u0 = *((const ushort4*)(xh16 + (size_t)s4a.x * 256) + lane);
        ushort4 u1 = *((const ushort4*)(xh16 + (size_t)s4a.y * 256) + lane);
        ushort4 u2 = *((const ushort4*)(xh16 + (size_t)s4a.z * 256) + lane);
        ushort4 u3 = *((const ushort4*)(xh16 + (size_t)s4a.w * 256) + lane);
        ushort4 u4 = *((const ushort4*)(xh16 + (size_t)s4b.x * 256) + lane);
        ushort4 u5 = *((const ushort4*)(xh16 + (size_t)s4b.y * 256) + lane);
        ushort4 u6 = *((const ushort4*)(xh16 + (size_t)s4b.z * 256) + lane);
        ushort4 u7 = *((const ushort4*)(xh16 + (size_t)s4b.w * 256) + lane);
        a0.x += bf2f(u0.x) * ca.x; a0.y += bf2f(u0.y) * ca.x; a0.z += bf2f(u0.z) * ca.x; a0.w += bf2f(u0.w) * ca.x;
        a1.x += bf2f(u1.x) * ca.y; a1.y += bf2f(u1.y) * ca.y; a1.z += bf2f(u1.z) * ca.y; a1.w += bf2f(u1.w) * ca.y;
        a2.x += bf2f(u2.x) * ca.z; a2.y += bf2f(u2.y) * ca.z; a2.z += bf2f(u2.z) * ca.z; a2.w += bf2f(u2.w) * ca.z;
        a3.x += bf2f(u3.x) * ca.w; a3.y += bf2f(u3.y) * ca.w; a3.z += bf2f(u3.z) * ca.w; a3.w += bf2f(u3.w) * ca.w;
        a0.x += bf2f(u4.x) * cb.x; a0.y += bf2f(u4.y) * cb.x; a0.z += bf2f(u4.z) * cb.x; a0.w += bf2f(u4.w) * cb.x;
        a1.x += bf2f(u5.x) * cb.y; a1.y += bf2f(u5.y) * cb.y; a1.z += bf2f(u5.z) * cb.y; a1.w += bf2f(u5.w) * cb.y;
        a2.x += bf2f(u6.x) * cb.z; a2.y += bf2f(u6.y) * cb.z; a2.z += bf2f(u6.z) * cb.z; a2.w += bf2f(u6.w) * cb.z;
        a3.x += bf2f(u7.x) * cb.w; a3.y += bf2f(u7.y) * cb.w; a3.z += bf2f(u7.z) * cb.w; a3.w += bf2f(u7.w) * cb.w;
    }
    for (; k + 4 <= kmax; k += 4) {
        int4 s4 = *(const int4*)&sv[k];
        float4 cc = *(const float4*)&alh[k];
        ushort4 u0 = *((const ushort4*)(xh16 + (size_t)s4.x * 256) + lane);
        ushort4 u1 = *((const ushort4*)(xh16 + (size_t)s4.y * 256) + lane);
        ushort4 u2 = *((const ushort4*)(xh16 + (size_t)s4.z * 256) + lane);
        ushort4 u3 = *((const ushort4*)(xh16 + (size_t)s4.w * 256) + lane);
        a0.x += bf2f(u0.x) * cc.x; a0.y += bf2f(u0.y) * cc.x; a0.z += bf2f(u0.z) * cc.x; a0.w += bf2f(u0.w) * cc.x;
        a1.x += bf2f(u1.x) * cc.y; a1.y += bf2f(u1.y) * cc.y; a1.z += bf2f(u1.z) * cc.y; a1.w += bf2f(u1.w) * cc.y;
        a2.x += bf2f(u2.x) * cc.z; a2.y += bf2f(u2.y) * cc.z; a2.z += bf2f(u2.z) * cc.z; a2.w += bf2f(u2.w) * cc.z;
        a3.x += bf2f(u3.x) * cc.w; a3.y += bf2f(u3.y) * cc.w; a3.z += bf2f(u3.z) * cc.w; a3.w += bf2f(u3.w) * cc.w;
    }
    for (; k < kmax; ++k) {
        int s = sv[k];
        float sc = alh[k];
        ushort4 uv = *((const ushort4*)(xh16 + (size_t)s * 256) + lane);
        a0.x += bf2f(uv.x) * sc; a0.y += bf2f(uv.y) * sc;
        a0.z += bf2f(uv.z) * sc; a0.w += bf2f(uv.w) * sc;
    }
    for (k = CAP; k < deg; ++k) {   // rare spill path
        int4 r = rec[o0 + k];
        float sc = w[(size_t)r.y * 4 + hh] * __int_as_float(r.w);
        ushort4 uv = *((const ushort4*)(xh16 + (size_t)r.x * 256) + lane);
        a0.x += bf2f(uv.x) * sc; a0.y += bf2f(uv.y) * sc;
        a0.z += bf2f(uv.z) * sc; a0.w += bf2f(uv.w) * sc;
    }
    float4 acc;
    acc.x = (a0.x + a1.x) + (a2.x + a3.x);
    acc.y = (a0.y + a1.y) + (a2.y + a3.y);
    acc.z = (a0.z + a1.z) + (a2.z + a3.z);
    acc.w = (a0.w + a1.w) + (a2.w + a3.w);
    if (houtf)  *(float4*)(houtf + (size_t)n * 256 + lane * 4) = acc;
    if (hout16) {
        ushort4 u = make_ushort4(f2bf(acc.x), f2bf(acc.y), f2bf(acc.z), f2bf(acc.w));
        *((ushort4*)(hout16 + (size_t)n * 256) + lane) = u;
    }
}

// ==================== K5: gemm layer2 ∥ edge-major w1 reconstruction ====================
__global__ __launch_bounds__(256) void gemm2_w1(const unsigned short* __restrict__ A16,
                                                const unsigned short* __restrict__ Bt16,
                                                unsigned short* __restrict__ C16,
                                                const float* __restrict__ a_src,
                                                const float* __restrict__ a_dst,
                                                float* __restrict__ asrc2,
                                                float* __restrict__ adst2,
                                                int M, int K, int gemmB,
                                                const int* __restrict__ src,
                                                const int* __restrict__ dstp,
                                                const float* __restrict__ edge_attr,
                                                const float* __restrict__ asrc1,
                                                const float* __restrict__ adst1,
                                                const float* __restrict__ mxrc,
                                                const float* __restrict__ ce1,
                                                float* __restrict__ w1, int E) {
    __shared__ unsigned short As[128][72];
    __shared__ unsigned short Bs[128][72];
    if ((int)blockIdx.x < gemmB) {
        gemm_core(A16, Bt16, C16, a_src, a_dst, asrc2, adst2, M, K,
                  blockIdx.x & 1, blockIdx.x >> 1, As, Bs);
    } else {
        const int stride = ((int)gridDim.x - gemmB) * 256;
        const float4 c4 = *(const float4*)ce1;
        for (int e = ((int)blockIdx.x - gemmB) * 256 + (int)threadIdx.x; e < E; e += stride) {
            int s = src[e], d = dstp[e];
            float ea = edge_attr[e];
            const float4 as4 = *(const float4*)(asrc1 + (size_t)s * 4);
            const float4 ad4 = *(const float4*)(adst1 + (size_t)d * 4);
            float4 a;
            a.x = as4.x + ad4.x + ea * c4.x;
            a.y = as4.y + ad4.y + ea * c4.y;
            a.z = as4.z + ad4.z + ea * c4.z;
            a.w = as4.w + ad4.w + ea * c4.w;
            a.x = a.x > 0.f ? a.x : NEG_SLOPE * a.x;
            a.y = a.y > 0.f ? a.y : NEG_SLOPE * a.y;
            a.z = a.z > 0.f ? a.z : NEG_SLOPE * a.z;
            a.w = a.w > 0.f ? a.w : NEG_SLOPE * a.w;
            const float4 mx = *(const float4*)(mxrc + (size_t)d * 8);
            const float4 rc = *(const float4*)(mxrc + (size_t)d * 8 + 4);
            float4 o;
            o.x = __expf(a.x - mx.x) * rc.x;
            o.y = __expf(a.y - mx.y) * rc.y;
            o.z = __expf(a.z - mx.z) * rc.z;
            o.w = __expf(a.w - mx.w) * rc.w;
            *(float4*)(w1 + (size_t)e * 4) = o;
        }
    }
}

extern "C" void kernel_launch(void* const* d_in, const int* in_sizes, int n_in,
                              void* d_out, int out_size, void* d_ws, size_t ws_size,
                              hipStream_t stream) {
    const float* x          = (const float*)d_in[0];
    const int*   ei         = (const int*)d_in[1];
    const float* edge_attr  = (const float*)d_in[3];
    const float* edge_atten = (const float*)d_in[4];
    const float* W1     = (const float*)d_in[5];
    const float* a_src1 = (const float*)d_in[6];
    const float* a_dst1 = (const float*)d_in[7];
    const float* W_e1   = (const float*)d_in[8];
    const float* a_e1   = (const float*)d_in[9];
    const float* b1     = (const float*)d_in[10];
    const float* W2     = (const float*)d_in[11];
    const float* a_src2 = (const float*)d_in[12];
    const float* a_dst2 = (const float*)d_in[13];
    const float* W_e2   = (const float*)d_in[14];
    const float* a_e2   = (const float*)d_in[15];
    const float* b2     = (const float*)d_in[16];

    const int N = in_sizes[0] / 128;   // 20000
    const int E = in_sizes[1] / 2;     // 640000
    const int* srcp = ei;
    const int* dstp = ei + E;

    char* ws = (char*)d_ws;
    int4* rec             = (int4*)ws;            ws += (size_t)E * 16;       // 16B-aligned first
    unsigned short* xh16  = (unsigned short*)ws;  ws += (size_t)N * 256 * 2;
    unsigned short* h116  = (unsigned short*)ws;  ws += (size_t)N * 256 * 2;
    unsigned short* Wt1   = (unsigned short*)ws;  ws += (size_t)256 * 128 * 2;
    unsigned short* Wt2   = (unsigned short*)ws;  ws += (size_t)256 * 256 * 2;
    float* asrc   = (float*)ws;                   ws += (size_t)N * 4 * 4;
    float* adst   = (float*)ws;                   ws += (size_t)N * 4 * 4;
    float* asrc2  = (float*)ws;                   ws += (size_t)N * 4 * 4;
    float* adst2  = (float*)ws;                   ws += (size_t)N * 4 * 4;
    float* mxrc   = (float*)ws;                   ws += (size_t)N * 8 * 4;
    float* ce     = (float*)ws;                   ws += 32;   // ce1[4], ce2[4]
    int* deg    = (int*)ws;                       ws += (size_t)N * 4;
    int* off    = (int*)ws;                       ws += (size_t)(N + 1) * 4;
    int* ghist  = (int*)ws;                       ws += (size_t)NB * N * 4;   // 10.24 MB

    // xb16 (bf16 x, N*128) ALIASES h116: live only hist_prep->gemm1_scan; h116 is
    // written by node_fused#1 strictly after gemm1_scan consumed xb16.
    unsigned short* xb16 = h116;

    float* hout2 = (float*)d_out;                 // N*256
    float* w1    = hout2 + (size_t)N * 256;       // E*4
    float* w2    = w1 + (size_t)E * 4;            // E*4

    const int chunk = (E + NB - 1) / NB;          // 5000
    const int gb = (N + 3) / 4;
    const int rows = (N + 127) / 128;
    const int gemmB = 2 * rows;                   // 128-wide column blocks
    const int scanB = (N + 255) / 256;            // 79
    const int wB = 512;

    // ---------------- pipeline (R7 structure; gemm v2 only — NB stays 128) ----------
    hist_prep<<<NB + 256, 512, 0, stream>>>(dstp, ghist, E, chunk, N, NB,
                                            x, W1, W2, W_e1, a_e1, W_e2, a_e2,
                                            xb16, Wt1, Wt2, ce);
    gemm1_scan<<<gemmB + scanB, 256, 0, stream>>>(xb16, Wt1, xh16, a_src1, a_dst1,
                                                  asrc, adst, N, 128, gemmB,
                                                  ghist, deg, N, NB);
    fill_scan<<<NB, 1024, 0, stream>>>(srcp, dstp, edge_attr, edge_atten,
                                       deg, ghist, off, rec, E, chunk, N);
    // layer-1 node pass: no w scatter; exports mx/rc per node
    node_fused<<<gb, 256, 0, stream>>>(rec, off, asrc, adst, ce, xh16, b1, w1,
                                       0, mxrc, (float*)nullptr, h116, N);
    // layer-2 gemm ∥ coalesced w1 reconstruction
    gemm2_w1<<<gemmB + wB, 256, 0, stream>>>(h116, Wt2, xh16, a_src2, a_dst2,
                                             asrc2, adst2, N, 256, gemmB,
                                             srcp, dstp, edge_attr,
                                             asrc, adst, mxrc, ce, w1, E);
    // layer-2 node pass: writes w2 directly + final output
    node_fused<<<gb, 256, 0, stream>>>(rec, off, asrc2, adst2, ce + 4, xh16, b2, w2,
                                       1, (float*)nullptr, hout2,
                                       (unsigned short*)nullptr, N);
}